// Round 4
// baseline (99.908 us; speedup 1.0000x reference)
//
#include <hip/hip_runtime.h>
#include <math.h>

// Hungarian matcher cost matrix:
//   C[n,t] = 5*L1(xyxy) + 2*(focal@label[t]) - 2*GIoU + 9999*inner
// N = 14400, T = 1024, C = 91. Output [N,T] f32 (59 MB).
//
// R4: kernel is latency-bound (all pipes <35%, VGPR=36 -> compiler
// serialized everything through a few registers; per-thread critical path =
// ds_read latency chains). Restructure for ILP: prefetch ALL 32 class-cost
// gathers + all 8 rows' constants into distinct registers BEFORE the math,
// then pure unrolled math, stores from distinct registers (fire-and-forget).
// Also: single rcp for giou (shared denominator uni*carea).

#define BN 8
#define BT 256
#define VT 4
#define TBL_STRIDE 96   // >= C, 16B-multiple

__global__ __launch_bounds__(BT) void matcher_kernel(
    const float* __restrict__ logits,   // [N, C]
    const float* __restrict__ boxes,    // [N, 4] cxcywh
    const float* __restrict__ points,   // [N, 2]
    const float* __restrict__ objs,     // [N, 1]
    const int*   __restrict__ labels,   // [T]
    const float* __restrict__ tboxes,   // [T, 4] cxcywh
    float* __restrict__ out,            // [N, T]
    int N, int C, int T)
{
    __shared__ float s_table[BN * TBL_STRIDE]; // focal class cost per (row, class)
    __shared__ float s_row[BN][8];             // x0,y0,x1,y1 | px,py,area1,po

    const int tid = threadIdx.x;
    const int rowBase = blockIdx.y * BN;
    const int t0 = (blockIdx.x * BT + tid) * VT;

    // ---- Phase 1a: per-row constants ----
    if (tid < BN) {
        int n = rowBase + tid;
        if (n < N) {
            float4 b = *(const float4*)(boxes + 4 * n);
            float x0 = b.x - 0.5f * b.z;
            float y0 = b.y - 0.5f * b.w;
            float x1 = b.x + 0.5f * b.z;
            float y1 = b.y + 0.5f * b.w;
            s_row[tid][0] = x0;
            s_row[tid][1] = y0;
            s_row[tid][2] = x1;
            s_row[tid][3] = y1;
            float2 p = *(const float2*)(points + 2 * n);
            s_row[tid][4] = p.x;
            s_row[tid][5] = p.y;
            s_row[tid][6] = (x1 - x0) * (y1 - y0);
            s_row[tid][7] = 1.0f / (1.0f + expf(-objs[n]));  // obj sigmoid
        }
    }
    __syncthreads();

    // ---- Phase 1b: focal class-cost table (pos - neg) for this block's rows ----
    for (int idx = tid; idx < BN * C; idx += BT) {
        int r = idx / C;
        int c = idx - r * C;
        int n = rowBase + r;
        float v = 0.0f;
        if (n < N) {
            float lg = logits[n * C + c];
            float ps = 1.0f / (1.0f + expf(-lg));
            float p = ps * s_row[r][7];
            float omp = 1.0f - p;
            float pos = 0.25f * (omp * omp) * (-logf(p + 1e-8f));
            float neg = 0.75f * (p * p) * (-logf(omp + 1e-8f));
            v = pos - neg;
        }
        s_table[r * TBL_STRIDE + c] = v;
    }
    __syncthreads();

    // ---- Phase 2: 4 target columns x 8 rows per thread, max ILP ----
    if (t0 + VT <= T && rowBase + BN <= N) {
        // Target data in registers
        int4 lv = *(const int4*)(labels + t0);
        int lab[VT];
        lab[0] = lv.x; lab[1] = lv.y; lab[2] = lv.z; lab[3] = lv.w;
        float tx0[VT], ty0[VT], tx1[VT], ty1[VT], tarea[VT];
        #pragma unroll
        for (int j = 0; j < VT; ++j) {
            float4 tb = *(const float4*)(tboxes + 4 * (t0 + j));
            tx0[j] = tb.x - 0.5f * tb.z;
            ty0[j] = tb.y - 0.5f * tb.w;
            tx1[j] = tb.x + 0.5f * tb.z;
            ty1[j] = tb.y + 0.5f * tb.w;
            tarea[j] = (tx1[j] - tx0[j]) * (ty1[j] - ty0[j]);
        }

        // Prefetch ALL class-cost gathers (32 independent ds_read_b32)
        float cc[BN][VT];
        #pragma unroll
        for (int r = 0; r < BN; ++r) {
            const float* trow = s_table + r * TBL_STRIDE;
            #pragma unroll
            for (int j = 0; j < VT; ++j)
                cc[r][j] = trow[lab[j]];
        }

        // Prefetch ALL row constants (16 broadcast ds_read_b128)
        float rx0[BN], ry0[BN], rx1[BN], ry1[BN], rpx[BN], rpy[BN], ra1[BN];
        #pragma unroll
        for (int r = 0; r < BN; ++r) {
            float4 ra = *(const float4*)&s_row[r][0];
            float4 rb = *(const float4*)&s_row[r][4];
            rx0[r] = ra.x; ry0[r] = ra.y; rx1[r] = ra.z; ry1[r] = ra.w;
            rpx[r] = rb.x; rpy[r] = rb.y; ra1[r] = rb.z;
        }

        // Pure math + fire-and-forget stores
        float* obase = out + (size_t)rowBase * T + t0;
        #pragma unroll
        for (int r = 0; r < BN; ++r) {
            float x0 = rx0[r], y0 = ry0[r], x1 = rx1[r], y1 = ry1[r];
            float px = rpx[r], py = rpy[r], a1 = ra1[r];

            float4 res;
            float* resp = (float*)&res;
            #pragma unroll
            for (int j = 0; j < VT; ++j) {
                // L1 on xyxy
                float l1 = fabsf(x0 - tx0[j]) + fabsf(y0 - ty0[j])
                         + fabsf(x1 - tx1[j]) + fabsf(y1 - ty1[j]);

                // intersection / union
                float iw = fminf(x1, tx1[j]) - fmaxf(x0, tx0[j]);
                float ih = fminf(y1, ty1[j]) - fmaxf(y0, ty0[j]);
                float inter = fmaxf(iw, 0.0f) * fmaxf(ih, 0.0f);
                float uni = (a1 + tarea[j]) - inter;

                // enclosing box (extents >= 0 since w,h >= 0)
                float cw = fmaxf(x1, tx1[j]) - fminf(x0, tx0[j]);
                float ch = fmaxf(y1, ty1[j]) - fminf(y0, ty0[j]);
                float carea = cw * ch;

                // giou = iou - (carea-uni)/carea with one rcp:
                //   R = 1/(uni*carea); iou = inter*carea*R;
                //   (carea-uni)/carea = uni*(carea-uni)*R
                float R = __builtin_amdgcn_rcpf(uni * carea);
                float giou = (inter * carea - uni * (carea - uni)) * R;

                // inner-point: exact reference op sequence (sign-exact)
                float left = px - tx0[j];
                float top = py - ty0[j];
                float right = tx1[j] - px;
                float bottom = ty1[j] - py;
                float mind = fminf(fminf(left, top), fminf(right, bottom));

                float Cv = fmaf(5.0f, l1, fmaf(2.0f, cc[r][j], -2.0f * giou));
                Cv += (mind >= 0.0f) ? 0.0f : 9999.0f;
                resp[j] = Cv;
            }
            *(float4*)(obase + (size_t)r * T) = res;
        }
    }
}

extern "C" void kernel_launch(void* const* d_in, const int* in_sizes, int n_in,
                              void* d_out, int out_size, void* d_ws, size_t ws_size,
                              hipStream_t stream) {
    const float* logits = (const float*)d_in[0];  // [bs,nq,nc]
    const float* boxes  = (const float*)d_in[1];  // [bs,nq,4]
    const float* points = (const float*)d_in[2];  // [bs,nq,2]
    const float* objs   = (const float*)d_in[3];  // [bs,nq,1]
    const int*   labels = (const int*)d_in[4];    // [T]
    const float* tboxes = (const float*)d_in[5];  // [T,4]
    float* out = (float*)d_out;

    int N = in_sizes[1] / 4;        // 14400
    int T = in_sizes[5] / 4;        // 1024
    int C = in_sizes[0] / N;        // 91

    dim3 grid((T + BT * VT - 1) / (BT * VT), (N + BN - 1) / BN);
    matcher_kernel<<<grid, BT, 0, stream>>>(logits, boxes, points, objs,
                                            labels, tboxes, out, N, C, T);
}